// Round 19
// baseline (116.042 us; speedup 1.0000x reference)
//
#include <hip/hip_runtime.h>
#include <hip/hip_bf16.h>
#include <cstddef>

// B=8, C=128, H=W=64, S=4 (16x16=256 blocks), 3 branches.
// INS padded NHWC bf16 [ib][66][66][128]; WG bf16 [i][tap][cc][co][32].
// Attention operands bf16: Qb,K row-major [n][128]; VT transposed [ib][ch][key].
// qkv weights bf16 in ORIGINAL layout [i][c][k] (B-operand rows). OB bf16.

typedef __bf16 bf16x8 __attribute__((ext_vector_type(8)));
typedef float f32x4 __attribute__((ext_vector_type(4)));

__device__ __forceinline__ unsigned short f2bf(float f) {
  unsigned int u = __float_as_uint(f);
  return (unsigned short)((u + 0x7fffu + ((u >> 16) & 1u)) >> 16);
}
__device__ __forceinline__ float bf2f(unsigned short h) {
  return __uint_as_float(((unsigned int)h) << 16);
}
__device__ __forceinline__ unsigned int packbf(float a, float b) {
  return (unsigned int)f2bf(a) | ((unsigned int)f2bf(b) << 16);
}

// Merged prep + input transform (one dispatch)
__global__ __launch_bounds__(256) void k_prep0(
    const float* __restrict__ conv_w, unsigned short* __restrict__ WG,
    const float* __restrict__ qw, const float* __restrict__ kw, const float* __restrict__ vw,
    unsigned short* __restrict__ qwB, unsigned short* __restrict__ kwB,
    unsigned short* __restrict__ vwB,
    const float* __restrict__ out_w, const float* __restrict__ c3d_w,
    float* __restrict__ comb2, const float* __restrict__ c3d_b,
    const float* __restrict__ out_b, float* __restrict__ fb,
    unsigned short* __restrict__ INS, float* __restrict__ ym,
    const float* __restrict__ F1, const float* __restrict__ F2,
    const float* __restrict__ F3) {
  int blk = blockIdx.x;
  int t = threadIdx.x;
  __shared__ alignas(16) unsigned short L[64 * 136];
  if (blk < 384) {
    int i = blk >> 7, co = blk & 127;
    float* Lw = (float*)L;
    const float* src = conv_w + (size_t)blk * 1152;
    for (int q = t; q < 1152; q += 256) Lw[q] = src[q];
    __syncthreads();
    for (int id = t; id < 576; id += 256) {
      int tap = id >> 6, cp = id & 63;
      int cc = cp >> 4, e = (cp & 15) * 2;
      unsigned int w = packbf(Lw[(cp * 2) * 9 + tap], Lw[(cp * 2 + 1) * 9 + tap]);
      *(unsigned int*)(WG + ((size_t)(((i * 9 + tap) * 4 + cc) * 128 + co)) * 32 + e) = w;
    }
    return;
  } else if (blk < 576) {
    int idx = (blk - 384) * 256 + t;  // contiguous bf16 cast, layout [i][c][k]
    qwB[idx] = f2bf(qw[idx]);
    kwB[idx] = f2bf(kw[idx]);
    vwB[idx] = f2bf(vw[idx]);
    return;
  } else if (blk < 768) {
    int idx = (blk - 576) * 256 + t;  // o*384 + j
    int j = idx % 384, o = idx / 384;
    int c = j & 127, d = j >> 7;
    float s = 0.f;
    for (int m = 0; m < 128; m++)
      s += out_w[o * 128 + m] * c3d_w[(m * 128 + c) * 3 + d];
    comb2[idx] = s;
    return;
  } else if (blk == 768) {
    if (t < 128) {
      float s = out_b[t];
      for (int m = 0; m < 128; m++) s += out_w[t * 128 + m] * c3d_b[m];
      fb[t] = s;
    }
    for (int z = t; z < 3072; z += 256) ym[z] = 0.f;
    return;
  } else if (blk < 793) {
    int ib = blk - 769;
    uint4 z = {0u, 0u, 0u, 0u};
    for (int id = t; id < 4160; id += 256) {
      int pxI = id >> 4, seg = id & 15;
      int yy, xxp;
      if (pxI < 66) { yy = 0; xxp = pxI; }
      else if (pxI < 132) { yy = 65; xxp = pxI - 66; }
      else if (pxI < 196) { yy = pxI - 131; xxp = 0; }
      else { yy = pxI - 195; xxp = 65; }
      *(uint4*)(INS + (((size_t)ib * 66 + yy) * 66 + xxp) * 128 + seg * 8) = z;
    }
    return;
  }
  int pidx = blk - 793;
  int y = pidx & 63, b = (pidx >> 6) & 7, i = pidx >> 9;
  int ib = i * 8 + b;
  if (i == 1) {
    int x = t & 63, cg = t >> 6;
    unsigned short* lrow = L + x * 136 + cg * 32;
    const float* src = F2 + (((size_t)b * 128 + cg * 32) * 64 + y) * 64 + x;
#pragma unroll 4
    for (int k = 0; k < 32; k += 2) {
      float a = src[(size_t)k * 4096];
      float c = src[(size_t)(k + 1) * 4096];
      *(unsigned int*)(lrow + k) = packbf(a, c);
    }
  } else if (i == 2) {
    int xp = t & 31, cg8 = t >> 5;
    const float* src = F3 + (((size_t)b * 128 + cg8 * 16) * 128 + 2 * y) * 128 + 4 * xp;
    unsigned short* l0 = L + (2 * xp) * 136 + cg8 * 16;
    unsigned short* l1 = L + (2 * xp + 1) * 136 + cg8 * 16;
#pragma unroll
    for (int k = 0; k < 16; ++k) {
      const float* p = src + (size_t)k * 16384;
      float4 a = *(const float4*)p;
      float4 c = *(const float4*)(p + 128);
      l0[k] = f2bf(0.25f * (a.x + a.y + c.x + c.y));
      l1[k] = f2bf(0.25f * (a.z + a.w + c.z + c.w));
    }
  } else {
    int x = t & 63, cg = t >> 6;
    unsigned short* lrow = L + x * 136 + cg * 32;
    int ky = y >> 1, kx = x >> 1;
    int y0, y1, x0, x1;
    float wy0, wx0;
    if (y & 1) { y0 = ky; y1 = (ky + 1 < 32) ? ky + 1 : 31; wy0 = 0.75f; }
    else       { y0 = (ky - 1 > 0) ? ky - 1 : 0; y1 = ky;   wy0 = 0.25f; }
    if (x & 1) { x0 = kx; x1 = (kx + 1 < 32) ? kx + 1 : 31; wx0 = 0.75f; }
    else       { x0 = (kx - 1 > 0) ? kx - 1 : 0; x1 = kx;   wx0 = 0.25f; }
    const float* base = F1 + ((size_t)b * 128 + cg * 32) * 1024;
#pragma unroll 4
    for (int k = 0; k < 32; k += 2) {
      float v[2];
#pragma unroll
      for (int kk = 0; kk < 2; ++kk) {
        const float* p = base + (size_t)(k + kk) * 1024;
        float top = wx0 * p[y0 * 32 + x0] + (1.f - wx0) * p[y0 * 32 + x1];
        float bot = wx0 * p[y1 * 32 + x0] + (1.f - wx0) * p[y1 * 32 + x1];
        v[kk] = wy0 * top + (1.f - wy0) * bot;
      }
      *(unsigned int*)(lrow + k) = packbf(v[0], v[1]);
    }
  }
  __syncthreads();
  unsigned short* dst = INS + (((size_t)ib * 66 + (y + 1)) * 66 + 1) * 128;
#pragma unroll
  for (int q = 0; q < 4; ++q) {
    int id = t + 256 * q;
    int xx = id >> 4, cseg = id & 15;
    uint4 v = *(const uint4*)(&L[xx * 136 + cseg * 8]);
    *(uint4*)(dst + (size_t)id * 8) = v;
  }
}

// Fused xavg + MFMA Q/K/Vb projections. block=(nc,b,i): 16 rows, 4 waves.
__global__ __launch_bounds__(256) void k_qkv(
    const unsigned short* __restrict__ INS,
    const unsigned short* __restrict__ qwB, const float* __restrict__ qb,
    const unsigned short* __restrict__ kwB, const float* __restrict__ kb,
    const unsigned short* __restrict__ vwB, const float* __restrict__ vb,
    unsigned short* __restrict__ Qb, unsigned short* __restrict__ Km,
    unsigned short* __restrict__ VT) {
  int nc = blockIdx.x, b = blockIdx.y, i = blockIdx.z;
  int ib = i * 8 + b;
  int qbase = nc * 16;
  int t = threadIdx.x;
  __shared__ alignas(16) unsigned short xb[16 * 136];
  {
    int n = t >> 4, cs = t & 15;
    int gn = qbase + n;
    int by = gn >> 4, bx = gn & 15;
    float acc[8];
#pragma unroll
    for (int e = 0; e < 8; ++e) acc[e] = 0.f;
#pragma unroll
    for (int ry = 0; ry < 4; ++ry) {
      int y = by * 4 + ry;
      const unsigned short* row = INS + (((size_t)ib * 66 + y + 1) * 66 + 1) * 128 + cs * 8;
#pragma unroll
      for (int rx = 0; rx < 4; ++rx) {
        int x = bx * 4 + rx;
        uint4 v0 = *(const uint4*)(row + (size_t)x * 128);
        unsigned int u[4] = {v0.x, v0.y, v0.z, v0.w};
#pragma unroll
        for (int q = 0; q < 4; ++q) {
          acc[2 * q] += bf2f((unsigned short)(u[q] & 0xffffu));
          acc[2 * q + 1] += bf2f((unsigned short)(u[q] >> 16));
        }
      }
    }
#pragma unroll
    for (int m = 0; m < 4; ++m)
      *(unsigned int*)(&xb[n * 136 + cs * 8 + 2 * m]) =
          packbf(acc[2 * m] * (1.f / 16.f), acc[2 * m + 1] * (1.f / 16.f));
  }
  __syncthreads();
  int w = t >> 6, l = t & 63;
  int lr = l & 15, lk = (l >> 4) * 8;
  int cbase = w * 32;
  bf16x8 ax[4];
#pragma unroll
  for (int ks = 0; ks < 4; ++ks)
    ax[ks] = *(const bf16x8*)(&xb[lr * 136 + ks * 32 + lk]);

#pragma unroll
  for (int which = 0; which < 3; ++which) {
    const unsigned short* wB = (which == 0) ? qwB : (which == 1) ? kwB : vwB;
    const float* bias = (which == 0) ? qb : (which == 1) ? kb : vb;
    f32x4 acc[2];
    acc[0] = {0.f, 0.f, 0.f, 0.f};
    acc[1] = acc[0];
#pragma unroll
    for (int ks = 0; ks < 4; ++ks)
#pragma unroll
      for (int nt = 0; nt < 2; ++nt) {
        bf16x8 bw = *(const bf16x8*)(wB + ((size_t)(i * 128 + cbase + nt * 16 + lr)) * 128 + ks * 32 + lk);
        acc[nt] = __builtin_amdgcn_mfma_f32_16x16x32_bf16(ax[ks], bw, acc[nt], 0, 0, 0);
      }
#pragma unroll
    for (int nt = 0; nt < 2; ++nt) {
      int c = cbase + nt * 16 + lr;
      float bv = bias[i * 128 + c];
#pragma unroll
      for (int r = 0; r < 4; ++r) {
        int n = (l >> 4) * 4 + r;
        float v = acc[nt][r] + bv;
        if (which == 0)
          Qb[((size_t)(ib * 256 + qbase + n)) * 128 + c] = f2bf(v);
        else if (which == 1)
          Km[((size_t)(ib * 256 + qbase + n)) * 128 + c] = f2bf(v);
        else
          VT[((size_t)(ib * 128 + c)) * 256 + qbase + n] = f2bf(16.f * v);
      }
    }
  }
}

// attention v3 (MFMA): block = (i,b,16 q-rows), grid (16,8,3). 4 waves. OB bf16.
__global__ __launch_bounds__(256) void k_attn(
    const unsigned short* __restrict__ Qb, const unsigned short* __restrict__ K,
    const unsigned short* __restrict__ VT, unsigned short* __restrict__ OB) {
  int nc = blockIdx.x, b = blockIdx.y, i = blockIdx.z;
  int ib = i * 8 + b;
  int qbase = nc * 16;
  int t = threadIdx.x;
  int w = t >> 6, l = t & 63;
  int lr = l & 15, lk = (l >> 4) * 8;
  __shared__ float Ss[16 * 260];
  __shared__ alignas(16) unsigned short Pb[16 * 280];

  const float SC = 0.08838834764831845f;
  {
    bf16x8 aq[4];
#pragma unroll
    for (int ks = 0; ks < 4; ++ks)
      aq[ks] = *(const bf16x8*)(Qb + ((size_t)(ib * 256 + qbase + lr)) * 128 + ks * 32 + lk);
    f32x4 acc[4];
#pragma unroll
    for (int nt = 0; nt < 4; ++nt) acc[nt] = {0.f, 0.f, 0.f, 0.f};
#pragma unroll
    for (int ks = 0; ks < 4; ++ks)
#pragma unroll
      for (int nt = 0; nt < 4; ++nt) {
        bf16x8 bk = *(const bf16x8*)(K + ((size_t)(ib * 256 + w * 64 + nt * 16 + lr)) * 128 + ks * 32 + lk);
        acc[nt] = __builtin_amdgcn_mfma_f32_16x16x32_bf16(aq[ks], bk, acc[nt], 0, 0, 0);
      }
#pragma unroll
    for (int nt = 0; nt < 4; ++nt)
#pragma unroll
      for (int r = 0; r < 4; ++r)
        Ss[((l >> 4) * 4 + r) * 260 + w * 64 + nt * 16 + lr] = acc[nt][r] * SC;
  }
  __syncthreads();
  {
    int n = t >> 4, ms = t & 15;
    float vals[16];
    float mx = -1e30f;
#pragma unroll
    for (int j = 0; j < 16; ++j) { vals[j] = Ss[n * 260 + ms + 16 * j]; mx = fmaxf(mx, vals[j]); }
    for (int d = 1; d < 16; d <<= 1) mx = fmaxf(mx, __shfl_xor(mx, d));
    float sum = 0.f;
#pragma unroll
    for (int j = 0; j < 16; ++j) { vals[j] = __expf(vals[j] - mx); sum += vals[j]; }
    for (int d = 1; d < 16; d <<= 1) sum += __shfl_xor(sum, d);
    float inv = 1.f / sum;
#pragma unroll
    for (int j = 0; j < 16; ++j) Pb[n * 280 + ms + 16 * j] = f2bf(vals[j] * inv);
  }
  __syncthreads();
  {
    f32x4 acc[2];
    acc[0] = {0.f, 0.f, 0.f, 0.f};
    acc[1] = acc[0];
#pragma unroll
    for (int ks = 0; ks < 8; ++ks) {
      bf16x8 ap = *(const bf16x8*)(&Pb[lr * 280 + ks * 32 + lk]);
#pragma unroll
      for (int nt = 0; nt < 2; ++nt) {
        bf16x8 bv = *(const bf16x8*)(VT + ((size_t)(ib * 128 + w * 32 + nt * 16 + lr)) * 256 + ks * 32 + lk);
        acc[nt] = __builtin_amdgcn_mfma_f32_16x16x32_bf16(ap, bv, acc[nt], 0, 0, 0);
      }
    }
    // OB bf16 store: lane holds 4 q-rows for channel ch; pack per-row scalar stores
#pragma unroll
    for (int nt = 0; nt < 2; ++nt)
#pragma unroll
      for (int r = 0; r < 4; ++r) {
        int q = (l >> 4) * 4 + r;
        int ch = w * 32 + nt * 16 + lr;
        OB[((size_t)(ib * 256 + qbase + q)) * 128 + ch] = f2bf(acc[nt][r]);
      }
  }
}

// conv3x3 MFMA implicit GEMM: TWO y-rows per block (128co x 128px), grid 32x8x3.
// r15 configuration; OB read as bf16 (uint2 = 4 channels).
__global__ __launch_bounds__(256) void k_conv(
    const unsigned short* __restrict__ INS, const unsigned short* __restrict__ WG,
    const float* __restrict__ conv_b, const unsigned short* __restrict__ OB,
    unsigned short* __restrict__ catT, float* __restrict__ Ysum) {
  int yr = blockIdx.x;
  int yp = ((yr & 7) << 2) | (yr >> 3);
  int y0 = yp * 2;
  int b = blockIdx.y, i = blockIdx.z;
  int ib = i * 8 + b;
  int t = threadIdx.x;
  __shared__ alignas(16) unsigned short smem[17408];
  int w = t >> 6, l = t & 63;
  int lr = l & 15, q4 = l >> 4;

  f32x4 acc[2][2][4];
#pragma unroll
  for (int ro = 0; ro < 2; ++ro)
#pragma unroll
    for (int s = 0; s < 2; s++)
#pragma unroll
      for (int p = 0; p < 4; p++) acc[ro][s][p] = 0.f;

  auto stageX = [&](int h) {
    for (int cI = t; cI < 2112; cI += 256) {
      int seg = cI & 7, rj = cI >> 3;
      int r = rj / 66, j = rj - r * 66;
      uint4 v = *(const uint4*)(INS + (((size_t)ib * 66 + y0 + r) * 66 + j) * 128 + h * 64 + seg * 8);
      *(uint4*)(&smem[(r * 66 + j) * 64 + ((seg ^ (j & 7)) * 8)]) = v;
    }
  };

  const unsigned short* wbase = WG + (size_t)(i * 9) * 4 * 128 * 32 + (w * 32 + lr) * 32 + q4 * 8;
  auto wload = [&](bf16x8* dst, int s) {
    int tap = s % 9, cc = s / 9;
    const unsigned short* wp = wbase + (size_t)(tap * 4 + cc) * 4096;
    dst[0] = *(const bf16x8*)(wp);
    dst[1] = *(const bf16x8*)(wp + 16 * 32);
  };
  bf16x8 wbuf[3][2];
  stageX(0);
  wload(wbuf[0], 0);
  wload(wbuf[1], 1);
  __syncthreads();

#pragma unroll
  for (int s = 0; s < 36; ++s) {
    if (s + 2 < 36) wload(wbuf[(s + 2) % 3], s + 2);
    int tap = s % 9;
    int cc2 = (s / 9) & 1;
    int dy = tap / 3, dx = tap - dy * 3;
    int sid = cc2 * 4 + q4;
#pragma unroll
    for (int ro = 0; ro < 2; ++ro) {
      bf16x8 bfv[4];
#pragma unroll
      for (int p = 0; p < 4; ++p) {
        int j = p * 16 + lr + dx;
        bfv[p] = *(const bf16x8*)(&smem[((dy + ro) * 66 + j) * 64 + ((sid ^ (j & 7)) * 8)]);
      }
#pragma unroll
      for (int sf = 0; sf < 2; ++sf)
#pragma unroll
        for (int p = 0; p < 4; ++p)
          acc[ro][sf][p] = __builtin_amdgcn_mfma_f32_16x16x32_bf16(wbuf[s % 3][sf], bfv[p], acc[ro][sf][p], 0, 0, 0);
    }
    if (s == 17) {
      __syncthreads();
      stageX(1);
      __syncthreads();
    }
  }
  __syncthreads();

  unsigned short* Tt = smem;  // [128 ploc][136 co]
  int cobase[2];
  cobase[0] = w * 32 + q4 * 4;
  cobase[1] = w * 32 + 16 + q4 * 4;
  float cb[2][4], ys[2][4];
#pragma unroll
  for (int sf = 0; sf < 2; ++sf)
#pragma unroll
    for (int q = 0; q < 4; ++q) {
      cb[sf][q] = conv_b[i * 128 + cobase[sf] + q];
      ys[sf][q] = 0.f;
    }
#pragma unroll
  for (int ro = 0; ro < 2; ++ro) {
    int nbase = ((y0 + ro) >> 2) * 16;
#pragma unroll
    for (int sf = 0; sf < 2; ++sf) {
#pragma unroll
      for (int p = 0; p < 4; ++p) {
        int px = p * 16 + lr;
        int n = nbase + (px >> 2);
        uint2 obu = *(const uint2*)(OB + ((size_t)(ib * 256 + n)) * 128 + cobase[sf]);
        float v0 = acc[ro][sf][p][0] + cb[sf][0] + bf2f((unsigned short)(obu.x & 0xffffu));
        float v1 = acc[ro][sf][p][1] + cb[sf][1] + bf2f((unsigned short)(obu.x >> 16));
        float v2 = acc[ro][sf][p][2] + cb[sf][2] + bf2f((unsigned short)(obu.y & 0xffffu));
        float v3 = acc[ro][sf][p][3] + cb[sf][3] + bf2f((unsigned short)(obu.y >> 16));
        ys[sf][0] += v0; ys[sf][1] += v1; ys[sf][2] += v2; ys[sf][3] += v3;
        int ploc = ro * 64 + px;
        *(unsigned int*)(&Tt[ploc * 136 + cobase[sf]]) = packbf(v0, v1);
        *(unsigned int*)(&Tt[ploc * 136 + cobase[sf] + 2]) = packbf(v2, v3);
      }
    }
  }
#pragma unroll
  for (int sf = 0; sf < 2; ++sf)
#pragma unroll
    for (int q = 0; q < 4; ++q) {
      float r = ys[sf][q];
      r += __shfl_xor(r, 1);
      r += __shfl_xor(r, 2);
      r += __shfl_xor(r, 4);
      r += __shfl_xor(r, 8);
      if (lr == 0) atomicAdd(&Ysum[b * 384 + i * 128 + cobase[sf] + q], r);
    }
  __syncthreads();
  for (int c2 = t; c2 < 2048; c2 += 256) {
    int ploc = c2 >> 4, seg = c2 & 15;
    uint4 v = *(const uint4*)(&Tt[ploc * 136 + seg * 8]);
    int yy = y0 + (ploc >> 6), xx = ploc & 63;
    *(uint4*)(catT + (((size_t)b * 4096) + yy * 64 + xx) * 384 + i * 128 + seg * 8) = v;
  }
}

// final GEMM with inline SE
__global__ __launch_bounds__(256) void k_final(
    const float* __restrict__ Ysum,
    const float* __restrict__ ca1_w, const float* __restrict__ ca1_b,
    const float* __restrict__ ca2_w, const float* __restrict__ ca2_b,
    const float* __restrict__ comb2, const unsigned short* __restrict__ catT,
    const float* __restrict__ fb, float* __restrict__ out) {
  int pc = blockIdx.x, b = blockIdx.y;
  int t = threadIdx.x;
  __shared__ alignas(16) unsigned short fsm[20480];
  __shared__ float ysh[384];
  __shared__ float sig[384];
  __shared__ float z1[24];
  unsigned short* Ab0 = fsm;
  unsigned short* Ab1 = fsm + 5120;
  unsigned short* Bb0 = fsm + 10240;
  unsigned short* Bb1 = fsm + 15360;

  int w = t >> 6, l = t & 63;
  int wo = w >> 1, wp = w & 1;
  int lr = l & 15, lk = (l >> 4) * 8;

  for (int j = t; j < 384; j += 256) ysh[j] = Ysum[b * 384 + j] * (1.f / 4096.f);
  __syncthreads();
  if (t < 24) {
    float s = ca1_b[t];
    for (int k = 0; k < 384; k++) s += ca1_w[t * 384 + k] * ysh[k];
    z1[t] = fmaxf(s, 0.f);
  }
  __syncthreads();
  for (int j = t; j < 384; j += 256) {
    float s = ca2_b[j];
#pragma unroll
    for (int k = 0; k < 24; k++) s += ca2_w[j * 24 + k] * z1[k];
    sig[j] = 1.f / (1.f + __expf(-s));
  }
  __syncthreads();

  f32x4 acc[4][4];
#pragma unroll
  for (int s = 0; s < 4; s++)
#pragma unroll
    for (int p = 0; p < 4; p++) acc[s][p] = 0.f;

  auto stageA = [&](unsigned short* Adst, int c) {
#pragma unroll
    for (int q = 0; q < 2; ++q) {
      int id = t + 256 * q;
      int o = id >> 2, seg = id & 3;
      int jb = c * 32 + seg * 8;
      const float* src = comb2 + (size_t)o * 384 + jb;
      float4 a = *(const float4*)src;
      float4 b4 = *(const float4*)(src + 4);
      alignas(16) unsigned short tmp[8];
      tmp[0] = f2bf(a.x * sig[jb + 0]);
      tmp[1] = f2bf(a.y * sig[jb + 1]);
      tmp[2] = f2bf(a.z * sig[jb + 2]);
      tmp[3] = f2bf(a.w * sig[jb + 3]);
      tmp[4] = f2bf(b4.x * sig[jb + 4]);
      tmp[5] = f2bf(b4.y * sig[jb + 5]);
      tmp[6] = f2bf(b4.z * sig[jb + 6]);
      tmp[7] = f2bf(b4.w * sig[jb + 7]);
      *(uint4*)(&Adst[o * 40 + seg * 8]) = *(uint4*)tmp;
    }
  };

  stageA(Ab0, 0);
  for (int q = 0; q < 2; ++q) {
    int id = t + 256 * q;
    int o = id >> 2, seg = id & 3;
    uint4 vb = *(const uint4*)(catT + ((size_t)b * 4096 + pc * 128 + o) * 384 + seg * 8);
    *(uint4*)(&Bb0[o * 40 + seg * 8]) = vb;
  }
  __syncthreads();

  for (int c = 0; c < 12; ++c) {
    unsigned short* Acur = (c & 1) ? Ab1 : Ab0;
    unsigned short* Bcur = (c & 1) ? Bb1 : Bb0;
    unsigned short* Anxt = (c & 1) ? Ab0 : Ab1;
    unsigned short* Bnxt = (c & 1) ? Bb0 : Bb1;
    uint4 bpf[2];
    if (c < 11) {
      stageA(Anxt, c + 1);
#pragma unroll
      for (int q = 0; q < 2; ++q) {
        int id = t + 256 * q;
        int o = id >> 2, seg = id & 3;
        bpf[q] = *(const uint4*)(catT + ((size_t)b * 4096 + pc * 128 + o) * 384 + (c + 1) * 32 + seg * 8);
      }
    }
    {
      bf16x8 af[4], bf_[4];
#pragma unroll
      for (int sf = 0; sf < 4; ++sf)
        af[sf] = *(const bf16x8*)(&Acur[(wo * 64 + sf * 16 + lr) * 40 + lk]);
#pragma unroll
      for (int p = 0; p < 4; ++p)
        bf_[p] = *(const bf16x8*)(&Bcur[(wp * 64 + p * 16 + lr) * 40 + lk]);
#pragma unroll
      for (int sf = 0; sf < 4; ++sf)
#pragma unroll
        for (int p = 0; p < 4; ++p)
          acc[sf][p] = __builtin_amdgcn_mfma_f32_16x16x32_bf16(af[sf], bf_[p], acc[sf][p], 0, 0, 0);
    }
    if (c < 11) {
#pragma unroll
      for (int q = 0; q < 2; ++q) {
        int id = t + 256 * q;
        int o = id >> 2, seg = id & 3;
        *(uint4*)(&Bnxt[o * 40 + seg * 8]) = bpf[q];
      }
    }
    __syncthreads();
  }

#pragma unroll
  for (int sf = 0; sf < 4; ++sf) {
    int obase = wo * 64 + sf * 16 + (l >> 4) * 4;
#pragma unroll
    for (int p = 0; p < 4; ++p) {
      int px = wp * 64 + p * 16 + lr;
#pragma unroll
      for (int q = 0; q < 4; ++q) {
        int o = obase + q;
        out[((size_t)(b * 128 + o)) * 4096 + pc * 128 + px] = acc[sf][p][q] + fb[o];
      }
    }
  }
}

extern "C" void kernel_launch(void* const* d_in, const int* in_sizes, int n_in,
                              void* d_out, int out_size, void* d_ws, size_t ws_size,
                              hipStream_t stream) {
  const float* F1 = (const float*)d_in[0];
  const float* F2 = (const float*)d_in[1];
  const float* F3 = (const float*)d_in[2];
  const float* conv_w = (const float*)d_in[3];
  const float* conv_b = (const float*)d_in[4];
  const float* qw = (const float*)d_in[5];
  const float* qb = (const float*)d_in[6];
  const float* kw = (const float*)d_in[7];
  const float* kb = (const float*)d_in[8];
  const float* vw = (const float*)d_in[9];
  const float* vb = (const float*)d_in[10];
  const float* ca1_w = (const float*)d_in[11];
  const float* ca1_b = (const float*)d_in[12];
  const float* ca2_w = (const float*)d_in[13];
  const float* ca2_b = (const float*)d_in[14];
  const float* c3d_w = (const float*)d_in[15];
  const float* c3d_b = (const float*)d_in[16];
  const float* out_w = (const float*)d_in[17];
  const float* out_b = (const float*)d_in[18];
  float* out = (float*)d_out;

  char* W = (char*)d_ws;
  unsigned short* INS  = (unsigned short*)W;                    // 26,763,264 B (padded 66x66)
  unsigned short* CATT = (unsigned short*)(W + 26763264);       // 25,165,824 B
  unsigned short* QmB = (unsigned short*)(W + 51929088);        // 1,572,864 (bf16)
  unsigned short* KmB = (unsigned short*)(W + 55074816);        // 1,572,864 (bf16)
  unsigned short* VTB = (unsigned short*)(W + 58220544);        // 1,572,864 (bf16, transposed)
  unsigned short* OBm = (unsigned short*)(W + 61366272);        // 1,572,864 (bf16)
  unsigned short* WG = (unsigned short*)(W + 64512000);         // 884,736
  unsigned short* QWB = (unsigned short*)(W + 65396736);        // 98,304 (bf16)
  unsigned short* KWB = (unsigned short*)(W + 65593344);        // 98,304
  unsigned short* VWB = (unsigned short*)(W + 65789952);        // 98,304
  float* COMB2 = (float*)(W + 65986560);                        // 196,608
  float* YM    = (float*)(W + 66183168);                        // 12,288
  float* FB    = (float*)(W + 66195456);                        // 512

  k_prep0<<<2329, 256, 0, stream>>>(conv_w, WG, qw, kw, vw, QWB, KWB, VWB,
                                    out_w, c3d_w, COMB2, c3d_b, out_b, FB, INS, YM,
                                    F1, F2, F3);
  k_qkv<<<dim3(16, 8, 3), 256, 0, stream>>>(INS, QWB, qb, KWB, kb, VWB, vb, QmB, KmB, VTB);
  k_attn<<<dim3(16, 8, 3), 256, 0, stream>>>(QmB, KmB, VTB, OBm);
  k_conv<<<dim3(32, 8, 3), 256, 0, stream>>>(INS, WG, conv_b, OBm, CATT, YM);
  k_final<<<dim3(32, 8), 256, 0, stream>>>(YM, ca1_w, ca1_b, ca2_w, ca2_b, COMB2, CATT, FB, out);
}

// Round 20
// 114.372 us; speedup vs baseline: 1.0146x; 1.0146x over previous
//
#include <hip/hip_runtime.h>
#include <hip/hip_bf16.h>
#include <cstddef>

// B=8, C=128, H=W=64, S=4 (16x16=256 blocks), 3 branches.
// INS padded NHWC bf16 [ib][66][66][128]; WG bf16 [i][tap][cc][co][32].
// Attention operands bf16: Qb,K row-major [n][128]; VT transposed [ib][ch][key].
// qkv weights bf16 in ORIGINAL layout [i][c][k] (B-operand rows).

typedef __bf16 bf16x8 __attribute__((ext_vector_type(8)));
typedef float f32x4 __attribute__((ext_vector_type(4)));

__device__ __forceinline__ unsigned short f2bf(float f) {
  unsigned int u = __float_as_uint(f);
  return (unsigned short)((u + 0x7fffu + ((u >> 16) & 1u)) >> 16);
}
__device__ __forceinline__ float bf2f(unsigned short h) {
  return __uint_as_float(((unsigned int)h) << 16);
}
__device__ __forceinline__ unsigned int packbf(float a, float b) {
  return (unsigned int)f2bf(a) | ((unsigned int)f2bf(b) << 16);
}

// Merged prep + input transform (one dispatch)
__global__ __launch_bounds__(256) void k_prep0(
    const float* __restrict__ conv_w, unsigned short* __restrict__ WG,
    const float* __restrict__ qw, const float* __restrict__ kw, const float* __restrict__ vw,
    unsigned short* __restrict__ qwB, unsigned short* __restrict__ kwB,
    unsigned short* __restrict__ vwB,
    const float* __restrict__ out_w, const float* __restrict__ c3d_w,
    float* __restrict__ comb2, const float* __restrict__ c3d_b,
    const float* __restrict__ out_b, float* __restrict__ fb,
    unsigned short* __restrict__ INS, float* __restrict__ ym,
    const float* __restrict__ F1, const float* __restrict__ F2,
    const float* __restrict__ F3) {
  int blk = blockIdx.x;
  int t = threadIdx.x;
  __shared__ alignas(16) unsigned short L[64 * 136];
  if (blk < 384) {
    int i = blk >> 7, co = blk & 127;
    float* Lw = (float*)L;
    const float* src = conv_w + (size_t)blk * 1152;
    for (int q = t; q < 1152; q += 256) Lw[q] = src[q];
    __syncthreads();
    for (int id = t; id < 576; id += 256) {
      int tap = id >> 6, cp = id & 63;
      int cc = cp >> 4, e = (cp & 15) * 2;
      unsigned int w = packbf(Lw[(cp * 2) * 9 + tap], Lw[(cp * 2 + 1) * 9 + tap]);
      *(unsigned int*)(WG + ((size_t)(((i * 9 + tap) * 4 + cc) * 128 + co)) * 32 + e) = w;
    }
    return;
  } else if (blk < 576) {
    int idx = (blk - 384) * 256 + t;  // contiguous bf16 cast, layout [i][c][k]
    qwB[idx] = f2bf(qw[idx]);
    kwB[idx] = f2bf(kw[idx]);
    vwB[idx] = f2bf(vw[idx]);
    return;
  } else if (blk < 768) {
    int idx = (blk - 576) * 256 + t;  // o*384 + j
    int j = idx % 384, o = idx / 384;
    int c = j & 127, d = j >> 7;
    float s = 0.f;
    for (int m = 0; m < 128; m++)
      s += out_w[o * 128 + m] * c3d_w[(m * 128 + c) * 3 + d];
    comb2[idx] = s;
    return;
  } else if (blk == 768) {
    if (t < 128) {
      float s = out_b[t];
      for (int m = 0; m < 128; m++) s += out_w[t * 128 + m] * c3d_b[m];
      fb[t] = s;
    }
    for (int z = t; z < 3072; z += 256) ym[z] = 0.f;
    return;
  } else if (blk < 793) {
    int ib = blk - 769;
    uint4 z = {0u, 0u, 0u, 0u};
    for (int id = t; id < 4160; id += 256) {
      int pxI = id >> 4, seg = id & 15;
      int yy, xxp;
      if (pxI < 66) { yy = 0; xxp = pxI; }
      else if (pxI < 132) { yy = 65; xxp = pxI - 66; }
      else if (pxI < 196) { yy = pxI - 131; xxp = 0; }
      else { yy = pxI - 195; xxp = 65; }
      *(uint4*)(INS + (((size_t)ib * 66 + yy) * 66 + xxp) * 128 + seg * 8) = z;
    }
    return;
  }
  int pidx = blk - 793;
  int y = pidx & 63, b = (pidx >> 6) & 7, i = pidx >> 9;
  int ib = i * 8 + b;
  if (i == 1) {
    int x = t & 63, cg = t >> 6;
    unsigned short* lrow = L + x * 136 + cg * 32;
    const float* src = F2 + (((size_t)b * 128 + cg * 32) * 64 + y) * 64 + x;
#pragma unroll 4
    for (int k = 0; k < 32; k += 2) {
      float a = src[(size_t)k * 4096];
      float c = src[(size_t)(k + 1) * 4096];
      *(unsigned int*)(lrow + k) = packbf(a, c);
    }
  } else if (i == 2) {
    int xp = t & 31, cg8 = t >> 5;
    const float* src = F3 + (((size_t)b * 128 + cg8 * 16) * 128 + 2 * y) * 128 + 4 * xp;
    unsigned short* l0 = L + (2 * xp) * 136 + cg8 * 16;
    unsigned short* l1 = L + (2 * xp + 1) * 136 + cg8 * 16;
#pragma unroll
    for (int k = 0; k < 16; ++k) {
      const float* p = src + (size_t)k * 16384;
      float4 a = *(const float4*)p;
      float4 c = *(const float4*)(p + 128);
      l0[k] = f2bf(0.25f * (a.x + a.y + c.x + c.y));
      l1[k] = f2bf(0.25f * (a.z + a.w + c.z + c.w));
    }
  } else {
    int x = t & 63, cg = t >> 6;
    unsigned short* lrow = L + x * 136 + cg * 32;
    int ky = y >> 1, kx = x >> 1;
    int y0, y1, x0, x1;
    float wy0, wx0;
    if (y & 1) { y0 = ky; y1 = (ky + 1 < 32) ? ky + 1 : 31; wy0 = 0.75f; }
    else       { y0 = (ky - 1 > 0) ? ky - 1 : 0; y1 = ky;   wy0 = 0.25f; }
    if (x & 1) { x0 = kx; x1 = (kx + 1 < 32) ? kx + 1 : 31; wx0 = 0.75f; }
    else       { x0 = (kx - 1 > 0) ? kx - 1 : 0; x1 = kx;   wx0 = 0.25f; }
    const float* base = F1 + ((size_t)b * 128 + cg * 32) * 1024;
#pragma unroll 4
    for (int k = 0; k < 32; k += 2) {
      float v[2];
#pragma unroll
      for (int kk = 0; kk < 2; ++kk) {
        const float* p = base + (size_t)(k + kk) * 1024;
        float top = wx0 * p[y0 * 32 + x0] + (1.f - wx0) * p[y0 * 32 + x1];
        float bot = wx0 * p[y1 * 32 + x0] + (1.f - wx0) * p[y1 * 32 + x1];
        v[kk] = wy0 * top + (1.f - wy0) * bot;
      }
      *(unsigned int*)(lrow + k) = packbf(v[0], v[1]);
    }
  }
  __syncthreads();
  unsigned short* dst = INS + (((size_t)ib * 66 + (y + 1)) * 66 + 1) * 128;
#pragma unroll
  for (int q = 0; q < 4; ++q) {
    int id = t + 256 * q;
    int xx = id >> 4, cseg = id & 15;
    uint4 v = *(const uint4*)(&L[xx * 136 + cseg * 8]);
    *(uint4*)(dst + (size_t)id * 8) = v;
  }
}

// Fused xavg + MFMA Q/K/Vb projections. block=(nc,b,i): 16 rows, 4 waves.
__global__ __launch_bounds__(256) void k_qkv(
    const unsigned short* __restrict__ INS,
    const unsigned short* __restrict__ qwB, const float* __restrict__ qb,
    const unsigned short* __restrict__ kwB, const float* __restrict__ kb,
    const unsigned short* __restrict__ vwB, const float* __restrict__ vb,
    unsigned short* __restrict__ Qb, unsigned short* __restrict__ Km,
    unsigned short* __restrict__ VT) {
  int nc = blockIdx.x, b = blockIdx.y, i = blockIdx.z;
  int ib = i * 8 + b;
  int qbase = nc * 16;
  int t = threadIdx.x;
  __shared__ alignas(16) unsigned short xb[16 * 136];
  {
    int n = t >> 4, cs = t & 15;
    int gn = qbase + n;
    int by = gn >> 4, bx = gn & 15;
    float acc[8];
#pragma unroll
    for (int e = 0; e < 8; ++e) acc[e] = 0.f;
#pragma unroll
    for (int ry = 0; ry < 4; ++ry) {
      int y = by * 4 + ry;
      const unsigned short* row = INS + (((size_t)ib * 66 + y + 1) * 66 + 1) * 128 + cs * 8;
#pragma unroll
      for (int rx = 0; rx < 4; ++rx) {
        int x = bx * 4 + rx;
        uint4 v0 = *(const uint4*)(row + (size_t)x * 128);
        unsigned int u[4] = {v0.x, v0.y, v0.z, v0.w};
#pragma unroll
        for (int q = 0; q < 4; ++q) {
          acc[2 * q] += bf2f((unsigned short)(u[q] & 0xffffu));
          acc[2 * q + 1] += bf2f((unsigned short)(u[q] >> 16));
        }
      }
    }
#pragma unroll
    for (int m = 0; m < 4; ++m)
      *(unsigned int*)(&xb[n * 136 + cs * 8 + 2 * m]) =
          packbf(acc[2 * m] * (1.f / 16.f), acc[2 * m + 1] * (1.f / 16.f));
  }
  __syncthreads();
  int w = t >> 6, l = t & 63;
  int lr = l & 15, lk = (l >> 4) * 8;
  int cbase = w * 32;
  bf16x8 ax[4];
#pragma unroll
  for (int ks = 0; ks < 4; ++ks)
    ax[ks] = *(const bf16x8*)(&xb[lr * 136 + ks * 32 + lk]);

#pragma unroll
  for (int which = 0; which < 3; ++which) {
    const unsigned short* wB = (which == 0) ? qwB : (which == 1) ? kwB : vwB;
    const float* bias = (which == 0) ? qb : (which == 1) ? kb : vb;
    f32x4 acc[2];
    acc[0] = {0.f, 0.f, 0.f, 0.f};
    acc[1] = acc[0];
#pragma unroll
    for (int ks = 0; ks < 4; ++ks)
#pragma unroll
      for (int nt = 0; nt < 2; ++nt) {
        bf16x8 bw = *(const bf16x8*)(wB + ((size_t)(i * 128 + cbase + nt * 16 + lr)) * 128 + ks * 32 + lk);
        acc[nt] = __builtin_amdgcn_mfma_f32_16x16x32_bf16(ax[ks], bw, acc[nt], 0, 0, 0);
      }
#pragma unroll
    for (int nt = 0; nt < 2; ++nt) {
      int c = cbase + nt * 16 + lr;
      float bv = bias[i * 128 + c];
#pragma unroll
      for (int r = 0; r < 4; ++r) {
        int n = (l >> 4) * 4 + r;
        float v = acc[nt][r] + bv;
        if (which == 0)
          Qb[((size_t)(ib * 256 + qbase + n)) * 128 + c] = f2bf(v);
        else if (which == 1)
          Km[((size_t)(ib * 256 + qbase + n)) * 128 + c] = f2bf(v);
        else
          VT[((size_t)(ib * 128 + c)) * 256 + qbase + n] = f2bf(16.f * v);
      }
    }
  }
}

// attention v3 (MFMA): block = (i,b,16 q-rows), grid (16,8,3). 4 waves.
__global__ __launch_bounds__(256) void k_attn(
    const unsigned short* __restrict__ Qb, const unsigned short* __restrict__ K,
    const unsigned short* __restrict__ VT, float* __restrict__ OB) {
  int nc = blockIdx.x, b = blockIdx.y, i = blockIdx.z;
  int ib = i * 8 + b;
  int qbase = nc * 16;
  int t = threadIdx.x;
  int w = t >> 6, l = t & 63;
  int lr = l & 15, lk = (l >> 4) * 8;
  __shared__ float Ss[16 * 260];
  __shared__ alignas(16) unsigned short Pb[16 * 280];

  const float SC = 0.08838834764831845f;
  {
    bf16x8 aq[4];
#pragma unroll
    for (int ks = 0; ks < 4; ++ks)
      aq[ks] = *(const bf16x8*)(Qb + ((size_t)(ib * 256 + qbase + lr)) * 128 + ks * 32 + lk);
    f32x4 acc[4];
#pragma unroll
    for (int nt = 0; nt < 4; ++nt) acc[nt] = {0.f, 0.f, 0.f, 0.f};
#pragma unroll
    for (int ks = 0; ks < 4; ++ks)
#pragma unroll
      for (int nt = 0; nt < 4; ++nt) {
        bf16x8 bk = *(const bf16x8*)(K + ((size_t)(ib * 256 + w * 64 + nt * 16 + lr)) * 128 + ks * 32 + lk);
        acc[nt] = __builtin_amdgcn_mfma_f32_16x16x32_bf16(aq[ks], bk, acc[nt], 0, 0, 0);
      }
#pragma unroll
    for (int nt = 0; nt < 4; ++nt)
#pragma unroll
      for (int r = 0; r < 4; ++r)
        Ss[((l >> 4) * 4 + r) * 260 + w * 64 + nt * 16 + lr] = acc[nt][r] * SC;
  }
  __syncthreads();
  {
    int n = t >> 4, ms = t & 15;
    float vals[16];
    float mx = -1e30f;
#pragma unroll
    for (int j = 0; j < 16; ++j) { vals[j] = Ss[n * 260 + ms + 16 * j]; mx = fmaxf(mx, vals[j]); }
    for (int d = 1; d < 16; d <<= 1) mx = fmaxf(mx, __shfl_xor(mx, d));
    float sum = 0.f;
#pragma unroll
    for (int j = 0; j < 16; ++j) { vals[j] = __expf(vals[j] - mx); sum += vals[j]; }
    for (int d = 1; d < 16; d <<= 1) sum += __shfl_xor(sum, d);
    float inv = 1.f / sum;
#pragma unroll
    for (int j = 0; j < 16; ++j) Pb[n * 280 + ms + 16 * j] = f2bf(vals[j] * inv);
  }
  __syncthreads();
  {
    f32x4 acc[2];
    acc[0] = {0.f, 0.f, 0.f, 0.f};
    acc[1] = acc[0];
#pragma unroll
    for (int ks = 0; ks < 8; ++ks) {
      bf16x8 ap = *(const bf16x8*)(&Pb[lr * 280 + ks * 32 + lk]);
#pragma unroll
      for (int nt = 0; nt < 2; ++nt) {
        bf16x8 bv = *(const bf16x8*)(VT + ((size_t)(ib * 128 + w * 32 + nt * 16 + lr)) * 256 + ks * 32 + lk);
        acc[nt] = __builtin_amdgcn_mfma_f32_16x16x32_bf16(ap, bv, acc[nt], 0, 0, 0);
      }
    }
#pragma unroll
    for (int nt = 0; nt < 2; ++nt)
#pragma unroll
      for (int r = 0; r < 4; ++r) {
        int q = (l >> 4) * 4 + r;
        int ch = w * 32 + nt * 16 + lr;
        OB[((size_t)(ib * 256 + qbase + q)) * 128 + ch] = acc[nt][r];
      }
  }
}

// conv3x3 MFMA implicit GEMM: TWO y-rows per block (128co x 128px), grid 32x8x3.
// r15 configuration (best measured): wave = 32-co slice x both rows,
// 8 ds_read_b128 + 2 coalesced wloads -> 16 MFMAs/step, depth-2 prefetch.
__global__ __launch_bounds__(256) void k_conv(
    const unsigned short* __restrict__ INS, const unsigned short* __restrict__ WG,
    const float* __restrict__ conv_b, const float* __restrict__ OB,
    unsigned short* __restrict__ catT, float* __restrict__ Ysum) {
  int yr = blockIdx.x;
  int yp = ((yr & 7) << 2) | (yr >> 3);
  int y0 = yp * 2;
  int b = blockIdx.y, i = blockIdx.z;
  int ib = i * 8 + b;
  int t = threadIdx.x;
  __shared__ alignas(16) unsigned short smem[17408];
  int w = t >> 6, l = t & 63;
  int lr = l & 15, q4 = l >> 4;

  f32x4 acc[2][2][4];
#pragma unroll
  for (int ro = 0; ro < 2; ++ro)
#pragma unroll
    for (int s = 0; s < 2; s++)
#pragma unroll
      for (int p = 0; p < 4; p++) acc[ro][s][p] = 0.f;

  auto stageX = [&](int h) {
    for (int cI = t; cI < 2112; cI += 256) {
      int seg = cI & 7, rj = cI >> 3;
      int r = rj / 66, j = rj - r * 66;
      uint4 v = *(const uint4*)(INS + (((size_t)ib * 66 + y0 + r) * 66 + j) * 128 + h * 64 + seg * 8);
      *(uint4*)(&smem[(r * 66 + j) * 64 + ((seg ^ (j & 7)) * 8)]) = v;
    }
  };

  const unsigned short* wbase = WG + (size_t)(i * 9) * 4 * 128 * 32 + (w * 32 + lr) * 32 + q4 * 8;
  auto wload = [&](bf16x8* dst, int s) {
    int tap = s % 9, cc = s / 9;
    const unsigned short* wp = wbase + (size_t)(tap * 4 + cc) * 4096;
    dst[0] = *(const bf16x8*)(wp);
    dst[1] = *(const bf16x8*)(wp + 16 * 32);
  };
  bf16x8 wbuf[3][2];
  stageX(0);
  wload(wbuf[0], 0);
  wload(wbuf[1], 1);
  __syncthreads();

#pragma unroll
  for (int s = 0; s < 36; ++s) {
    if (s + 2 < 36) wload(wbuf[(s + 2) % 3], s + 2);
    int tap = s % 9;
    int cc2 = (s / 9) & 1;
    int dy = tap / 3, dx = tap - dy * 3;
    int sid = cc2 * 4 + q4;
#pragma unroll
    for (int ro = 0; ro < 2; ++ro) {
      bf16x8 bfv[4];
#pragma unroll
      for (int p = 0; p < 4; ++p) {
        int j = p * 16 + lr + dx;
        bfv[p] = *(const bf16x8*)(&smem[((dy + ro) * 66 + j) * 64 + ((sid ^ (j & 7)) * 8)]);
      }
#pragma unroll
      for (int sf = 0; sf < 2; ++sf)
#pragma unroll
        for (int p = 0; p < 4; ++p)
          acc[ro][sf][p] = __builtin_amdgcn_mfma_f32_16x16x32_bf16(wbuf[s % 3][sf], bfv[p], acc[ro][sf][p], 0, 0, 0);
    }
    if (s == 17) {
      __syncthreads();
      stageX(1);
      __syncthreads();
    }
  }
  __syncthreads();

  unsigned short* Tt = smem;  // [128 ploc][136 co]
  int cobase[2];
  cobase[0] = w * 32 + q4 * 4;
  cobase[1] = w * 32 + 16 + q4 * 4;
  float cb[2][4], ys[2][4];
#pragma unroll
  for (int sf = 0; sf < 2; ++sf)
#pragma unroll
    for (int q = 0; q < 4; ++q) {
      cb[sf][q] = conv_b[i * 128 + cobase[sf] + q];
      ys[sf][q] = 0.f;
    }
#pragma unroll
  for (int ro = 0; ro < 2; ++ro) {
    int nbase = ((y0 + ro) >> 2) * 16;
#pragma unroll
    for (int sf = 0; sf < 2; ++sf) {
#pragma unroll
      for (int p = 0; p < 4; ++p) {
        int px = p * 16 + lr;
        int n = nbase + (px >> 2);
        float4 obv = *(const float4*)(OB + ((size_t)(ib * 256 + n)) * 128 + cobase[sf]);
        float v0 = acc[ro][sf][p][0] + cb[sf][0] + obv.x;
        float v1 = acc[ro][sf][p][1] + cb[sf][1] + obv.y;
        float v2 = acc[ro][sf][p][2] + cb[sf][2] + obv.z;
        float v3 = acc[ro][sf][p][3] + cb[sf][3] + obv.w;
        ys[sf][0] += v0; ys[sf][1] += v1; ys[sf][2] += v2; ys[sf][3] += v3;
        int ploc = ro * 64 + px;
        *(unsigned int*)(&Tt[ploc * 136 + cobase[sf]]) = packbf(v0, v1);
        *(unsigned int*)(&Tt[ploc * 136 + cobase[sf] + 2]) = packbf(v2, v3);
      }
    }
  }
#pragma unroll
  for (int sf = 0; sf < 2; ++sf)
#pragma unroll
    for (int q = 0; q < 4; ++q) {
      float r = ys[sf][q];
      r += __shfl_xor(r, 1);
      r += __shfl_xor(r, 2);
      r += __shfl_xor(r, 4);
      r += __shfl_xor(r, 8);
      if (lr == 0) atomicAdd(&Ysum[b * 384 + i * 128 + cobase[sf] + q], r);
    }
  __syncthreads();
  for (int c2 = t; c2 < 2048; c2 += 256) {
    int ploc = c2 >> 4, seg = c2 & 15;
    uint4 v = *(const uint4*)(&Tt[ploc * 136 + seg * 8]);
    int yy = y0 + (ploc >> 6), xx = ploc & 63;
    *(uint4*)(catT + (((size_t)b * 4096) + yy * 64 + xx) * 384 + i * 128 + seg * 8) = v;
  }
}

// final GEMM with inline SE
__global__ __launch_bounds__(256) void k_final(
    const float* __restrict__ Ysum,
    const float* __restrict__ ca1_w, const float* __restrict__ ca1_b,
    const float* __restrict__ ca2_w, const float* __restrict__ ca2_b,
    const float* __restrict__ comb2, const unsigned short* __restrict__ catT,
    const float* __restrict__ fb, float* __restrict__ out) {
  int pc = blockIdx.x, b = blockIdx.y;
  int t = threadIdx.x;
  __shared__ alignas(16) unsigned short fsm[20480];
  __shared__ float ysh[384];
  __shared__ float sig[384];
  __shared__ float z1[24];
  unsigned short* Ab0 = fsm;
  unsigned short* Ab1 = fsm + 5120;
  unsigned short* Bb0 = fsm + 10240;
  unsigned short* Bb1 = fsm + 15360;

  int w = t >> 6, l = t & 63;
  int wo = w >> 1, wp = w & 1;
  int lr = l & 15, lk = (l >> 4) * 8;

  for (int j = t; j < 384; j += 256) ysh[j] = Ysum[b * 384 + j] * (1.f / 4096.f);
  __syncthreads();
  if (t < 24) {
    float s = ca1_b[t];
    for (int k = 0; k < 384; k++) s += ca1_w[t * 384 + k] * ysh[k];
    z1[t] = fmaxf(s, 0.f);
  }
  __syncthreads();
  for (int j = t; j < 384; j += 256) {
    float s = ca2_b[j];
#pragma unroll
    for (int k = 0; k < 24; k++) s += ca2_w[j * 24 + k] * z1[k];
    sig[j] = 1.f / (1.f + __expf(-s));
  }
  __syncthreads();

  f32x4 acc[4][4];
#pragma unroll
  for (int s = 0; s < 4; s++)
#pragma unroll
    for (int p = 0; p < 4; p++) acc[s][p] = 0.f;

  auto stageA = [&](unsigned short* Adst, int c) {
#pragma unroll
    for (int q = 0; q < 2; ++q) {
      int id = t + 256 * q;
      int o = id >> 2, seg = id & 3;
      int jb = c * 32 + seg * 8;
      const float* src = comb2 + (size_t)o * 384 + jb;
      float4 a = *(const float4*)src;
      float4 b4 = *(const float4*)(src + 4);
      alignas(16) unsigned short tmp[8];
      tmp[0] = f2bf(a.x * sig[jb + 0]);
      tmp[1] = f2bf(a.y * sig[jb + 1]);
      tmp[2] = f2bf(a.z * sig[jb + 2]);
      tmp[3] = f2bf(a.w * sig[jb + 3]);
      tmp[4] = f2bf(b4.x * sig[jb + 4]);
      tmp[5] = f2bf(b4.y * sig[jb + 5]);
      tmp[6] = f2bf(b4.z * sig[jb + 6]);
      tmp[7] = f2bf(b4.w * sig[jb + 7]);
      *(uint4*)(&Adst[o * 40 + seg * 8]) = *(uint4*)tmp;
    }
  };

  stageA(Ab0, 0);
  for (int q = 0; q < 2; ++q) {
    int id = t + 256 * q;
    int o = id >> 2, seg = id & 3;
    uint4 vb = *(const uint4*)(catT + ((size_t)b * 4096 + pc * 128 + o) * 384 + seg * 8);
    *(uint4*)(&Bb0[o * 40 + seg * 8]) = vb;
  }
  __syncthreads();

  for (int c = 0; c < 12; ++c) {
    unsigned short* Acur = (c & 1) ? Ab1 : Ab0;
    unsigned short* Bcur = (c & 1) ? Bb1 : Bb0;
    unsigned short* Anxt = (c & 1) ? Ab0 : Ab1;
    unsigned short* Bnxt = (c & 1) ? Bb0 : Bb1;
    uint4 bpf[2];
    if (c < 11) {
      stageA(Anxt, c + 1);
#pragma unroll
      for (int q = 0; q < 2; ++q) {
        int id = t + 256 * q;
        int o = id >> 2, seg = id & 3;
        bpf[q] = *(const uint4*)(catT + ((size_t)b * 4096 + pc * 128 + o) * 384 + (c + 1) * 32 + seg * 8);
      }
    }
    {
      bf16x8 af[4], bf_[4];
#pragma unroll
      for (int sf = 0; sf < 4; ++sf)
        af[sf] = *(const bf16x8*)(&Acur[(wo * 64 + sf * 16 + lr) * 40 + lk]);
#pragma unroll
      for (int p = 0; p < 4; ++p)
        bf_[p] = *(const bf16x8*)(&Bcur[(wp * 64 + p * 16 + lr) * 40 + lk]);
#pragma unroll
      for (int sf = 0; sf < 4; ++sf)
#pragma unroll
        for (int p = 0; p < 4; ++p)
          acc[sf][p] = __builtin_amdgcn_mfma_f32_16x16x32_bf16(af[sf], bf_[p], acc[sf][p], 0, 0, 0);
    }
    if (c < 11) {
#pragma unroll
      for (int q = 0; q < 2; ++q) {
        int id = t + 256 * q;
        int o = id >> 2, seg = id & 3;
        *(uint4*)(&Bnxt[o * 40 + seg * 8]) = bpf[q];
      }
    }
    __syncthreads();
  }

#pragma unroll
  for (int sf = 0; sf < 4; ++sf) {
    int obase = wo * 64 + sf * 16 + (l >> 4) * 4;
#pragma unroll
    for (int p = 0; p < 4; ++p) {
      int px = wp * 64 + p * 16 + lr;
#pragma unroll
      for (int q = 0; q < 4; ++q) {
        int o = obase + q;
        out[((size_t)(b * 128 + o)) * 4096 + pc * 128 + px] = acc[sf][p][q] + fb[o];
      }
    }
  }
}

extern "C" void kernel_launch(void* const* d_in, const int* in_sizes, int n_in,
                              void* d_out, int out_size, void* d_ws, size_t ws_size,
                              hipStream_t stream) {
  const float* F1 = (const float*)d_in[0];
  const float* F2 = (const float*)d_in[1];
  const float* F3 = (const float*)d_in[2];
  const float* conv_w = (const float*)d_in[3];
  const float* conv_b = (const float*)d_in[4];
  const float* qw = (const float*)d_in[5];
  const float* qb = (const float*)d_in[6];
  const float* kw = (const float*)d_in[7];
  const float* kb = (const float*)d_in[8];
  const float* vw = (const float*)d_in[9];
  const float* vb = (const float*)d_in[10];
  const float* ca1_w = (const float*)d_in[11];
  const float* ca1_b = (const float*)d_in[12];
  const float* ca2_w = (const float*)d_in[13];
  const float* ca2_b = (const float*)d_in[14];
  const float* c3d_w = (const float*)d_in[15];
  const float* c3d_b = (const float*)d_in[16];
  const float* out_w = (const float*)d_in[17];
  const float* out_b = (const float*)d_in[18];
  float* out = (float*)d_out;

  char* W = (char*)d_ws;
  unsigned short* INS  = (unsigned short*)W;                    // 26,763,264 B (padded 66x66)
  unsigned short* CATT = (unsigned short*)(W + 26763264);       // 25,165,824 B
  unsigned short* QmB = (unsigned short*)(W + 51929088);        // 1,572,864 (bf16)
  unsigned short* KmB = (unsigned short*)(W + 55074816);        // 1,572,864 (bf16)
  unsigned short* VTB = (unsigned short*)(W + 58220544);        // 1,572,864 (bf16, transposed)
  float* OBm   = (float*)(W + 61366272);                        // 3,145,728
  unsigned short* WG = (unsigned short*)(W + 64512000);         // 884,736
  unsigned short* QWB = (unsigned short*)(W + 65396736);        // 98,304 (bf16)
  unsigned short* KWB = (unsigned short*)(W + 65593344);        // 98,304
  unsigned short* VWB = (unsigned short*)(W + 65789952);        // 98,304
  float* COMB2 = (float*)(W + 65986560);                        // 196,608
  float* YM    = (float*)(W + 66183168);                        // 12,288
  float* FB    = (float*)(W + 66195456);                        // 512

  k_prep0<<<2329, 256, 0, stream>>>(conv_w, WG, qw, kw, vw, QWB, KWB, VWB,
                                    out_w, c3d_w, COMB2, c3d_b, out_b, FB, INS, YM,
                                    F1, F2, F3);
  k_qkv<<<dim3(16, 8, 3), 256, 0, stream>>>(INS, QWB, qb, KWB, kb, VWB, vb, QmB, KmB, VTB);
  k_attn<<<dim3(16, 8, 3), 256, 0, stream>>>(QmB, KmB, VTB, OBm);
  k_conv<<<dim3(32, 8, 3), 256, 0, stream>>>(INS, WG, conv_b, OBm, CATT, YM);
  k_final<<<dim3(32, 8), 256, 0, stream>>>(YM, ca1_w, ca1_b, ca2_w, ca2_b, COMB2, CATT, FB, out);
}